// Round 13
// baseline (175.692 us; speedup 1.0000x reference)
//
#include <hip/hip_runtime.h>
#include <math.h>

// ConvolutionalCapsule with EM routing, fully fused. Round-13 = R7 shape
// (512 threads, grid 288, one position/block, LDS-staged tile, no spill)
// + R12 packed math (proven identical) + ONE new mechanism:
//   E-passes process TWO i's per loop trip with BATCHED softmax chains:
//   both exp2s, both DPP row-sums, then both shfl_xor(16) LDS round-trips
//   issued back-to-back so the second's latency overlaps the first's.
// Rationale (R6-R12 accounting): duration = per-wave SERIAL wall time.
// All throughput resources nulled (TLP R9/R10, instr count R12, LDS-op
// count R11, spills R12, W-prefetch R8). Every win was a dependency-CHAIN
// cut (R6 -48us, R7 -8us). The rolled j-loop exposes each iteration's
// full chain (LDS read -> V -> quad -> exp2 -> DPP -> shfl(LDS) -> rcp)
// 54x back-to-back; intra-wave ILP across iterations is the one untested
// lever (R8 covered only the W load, whose latency was already hidden).
// Pass 0 has no softmax chain => stays rolled. 512-thr shape: VGPR cap
// ~128 at unchanged occupancy (R1-R5 lesson: 1024-thr is hard-capped 64).
// Proven set carried: Kmax shift, parallel statsA/B, DPP row reduce,
// I2L pre-scaled by log2e + pre-negated, ST=17 bijective banks, packing.
// Thread map: c = t&31, isub = t>>5 (0..15), i = isub*18 + j.

#define EPSF 1e-7f
#define KKI 288
#define NC 32
#define NTHREADS 512
#define IPT 18          // KKI / 16 half-waves
#define ST 17           // padded stride: (17c+d)%32 bijective over c
#define L2E 1.4426950408889634f

typedef float f32x2 __attribute__((ext_vector_type(2)));

__device__ __forceinline__ float rcp_fast(float v) { return __builtin_amdgcn_rcpf(v); }
__device__ __forceinline__ f32x2 pk_fma(f32x2 a, f32x2 b, f32x2 c) {
    return __builtin_elementwise_fma(a, b, c);   // -> v_pk_fma_f32
}

// DPP-based cross-lane (VALU pipe; proven R7)
template <int CTRL>
__device__ __forceinline__ float dpp_mov_f(float x) {
    return __int_as_float(__builtin_amdgcn_update_dpp(
        0, __float_as_int(x), CTRL, 0xF, 0xF, true));
}
__device__ __forceinline__ float row_sum16(float x) {
    x += dpp_mov_f<0xB1>(x);    // quad_perm xor1
    x += dpp_mov_f<0x4E>(x);    // quad_perm xor2
    x += dpp_mov_f<0x124>(x);   // row_ror:4
    x += dpp_mov_f<0x128>(x);   // row_ror:8
    return x;
}
__device__ __forceinline__ float row_max16(float x) {
    x = fmaxf(x, dpp_mov_f<0xB1>(x));
    x = fmaxf(x, dpp_mov_f<0x4E>(x));
    x = fmaxf(x, dpp_mov_f<0x124>(x));
    x = fmaxf(x, dpp_mov_f<0x128>(x));
    return x;
}

__global__ __launch_bounds__(NTHREADS)
void caps_em_kernel(const float* __restrict__ x, const float* __restrict__ Wg,
                    const float* __restrict__ beta_v, const float* __restrict__ beta_a,
                    float* __restrict__ out)
{
    __shared__ float MpL[KKI * 16];   // patch poses
    __shared__ float apL[KKI];        // patch activations
    __shared__ float T1L[NC * ST];    // sum_i Rw*v      (per iteration)
    __shared__ float S1L[NC * ST];    // sum_i v         (iteration-invariant)
    __shared__ float S2L[NC * ST];    // sum_i v^2       (iteration-invariant)
    __shared__ float ML[NC * ST];     // M
    __shared__ float I2L[NC * ST];    // 0.5/var * log2e (pre-scaled)
    __shared__ float RsumL[NC];
    __shared__ float constL[NC];      // Kc = log(a_j+eps) - sum_d log(stdv+eps)
    __shared__ float slogL[NC];
    __shared__ float costL[NC];
    __shared__ float aoutL[NC];       // sigmoid(a_j)
    __shared__ float KmaxL;           // max_c Kc

    const int t = threadIdx.x;
    const int bid = blockIdx.x;           // b*144 + ho*12 + wo
    const int b = bid / 144;
    const int rem = bid - b * 144;
    const int ho = rem / 12;
    const int wo = rem - ho * 12;

    const int c = t & 31;
    const int isub = t >> 5;              // 0..15
    const int iBase = isub * IPT;

    // ---- stage patch tile: Mp[i][0..15], ap[i], i = p*32+cin, p = di*3+dj ----
    for (int idx = t; idx < KKI * 17; idx += NTHREADS) {
        int i = idx / 17;
        int e = idx - i * 17;
        int p = i >> 5, cin = i & 31;
        int di = p / 3, dj = p - di * 3;
        float vx = x[(((b * 14 + (ho + di)) * 14 + (wo + dj)) * 32 + cin) * 17 + e];
        if (e < 16) MpL[i * 16 + e] = vx; else apL[i] = vx;
    }
    for (int idx = t; idx < NC * ST; idx += NTHREADS) { T1L[idx] = 0.f; S1L[idx] = 0.f; S2L[idx] = 0.f; }
    if (t < NC) RsumL[t] = 0.f;
    __syncthreads();

    // stats A: all 512 threads, one per (cc = t>>4, d = t&15);
    // d = lane bits 0-3 => pure-DPP row sum for slog.
    auto statsA = [&]() {
        const int cc = t >> 4, d = t & 15;
        float rsum = RsumL[cc];
        float m = T1L[cc * ST + d] * rcp_fast(rsum);
        float var = S2L[cc * ST + d] - 2.f * m * S1L[cc * ST + d] + 288.f * m * m;
        var = fmaxf(var, 0.f);
        float lg = logf(sqrtf(var) + EPSF);
        ML[cc * ST + d] = m;
        I2L[cc * ST + d] = 0.5f * L2E * rcp_fast(var);
        float sl = row_sum16(lg);
        if (d == 0) {
            slogL[cc] = sl;
            costL[cc] = rsum * (16.f * beta_v[cc] + sl);
        }
    };
    // stats B: cross-capsule mean/std + activation + Kmax (32 threads).
    auto statsB = [&](float inv_temp) {
        if (t < 32) {
            float cost = costL[t];
            float csum = row_sum16(cost); csum += __shfl_xor(csum, 16);
            float c_mean = csum * 0.03125f;
            float diff = cost - c_mean;
            float dsq = row_sum16(diff * diff); dsq += __shfl_xor(dsq, 16);
            float c_stdv = sqrtf(dsq * 0.03125f);
            float a_cost = beta_a[t] + (c_mean - cost) * rcp_fast(c_stdv + EPSF);
            float a_j = 1.f / (1.f + expf(-inv_temp * a_cost));
            float kc = logf(a_j + EPSF) - slogL[t];
            constL[t] = kc;
            aoutL[t] = 1.f / (1.f + expf(-a_j));
            float km = row_max16(kc); km = fmaxf(km, __shfl_xor(km, 16));
            if (t == 0) KmaxL = km;
        }
    };

    // packed vote compute: vv[p*2+rr] = (v[p*4+2rr], v[p*4+2rr+1])
    auto computeV = [&](const float (&wa)[16], const float (&ma)[16], f32x2 (&vv)[8]) {
        const f32x2* w2 = (const f32x2*)wa;
        #pragma unroll
        for (int p = 0; p < 4; ++p) {
            f32x2 m0 = ma[p * 4 + 0], m1 = ma[p * 4 + 1];
            f32x2 m2 = ma[p * 4 + 2], m3 = ma[p * 4 + 3];
            #pragma unroll
            for (int rr = 0; rr < 2; ++rr) {
                f32x2 acc = m0 * w2[0 * 2 + rr];
                acc = pk_fma(m1, w2[1 * 2 + rr], acc);
                acc = pk_fma(m2, w2[2 * 2 + rr], acc);
                acc = pk_fma(m3, w2[3 * 2 + rr], acc);
                vv[p * 2 + rr] = acc;
            }
        }
    };
    auto loadFrag = [&](int i, float (&wa)[16], float (&ma)[16]) {
        const float4* w4 = (const float4*)(Wg + ((size_t)((i << 5) + c) << 4));
        ((float4*)wa)[0] = w4[0]; ((float4*)wa)[1] = w4[1];
        ((float4*)wa)[2] = w4[2]; ((float4*)wa)[3] = w4[3];
        const float4* mp4 = (const float4*)(MpL + (i << 4));
        ((float4*)ma)[0] = mp4[0]; ((float4*)ma)[1] = mp4[1];
        ((float4*)ma)[2] = mp4[2]; ((float4*)ma)[3] = mp4[3];
    };

    // ---- pass 0: R uniform 1/32 -> Rw = ap/32; also build S1,S2 ----
    {
        f32x2 t12[8], s12[8], s22[8];
        #pragma unroll
        for (int dd = 0; dd < 8; ++dd) { t12[dd] = 0.f; s12[dd] = 0.f; s22[dd] = 0.f; }
        float rsum = 0.f;
        for (int j = 0; j < IPT; ++j) {
            const int i = iBase + j;
            float wa[16], ma[16];
            loadFrag(i, wa, ma);
            float rw = apL[i] * 0.03125f;
            rsum += rw;
            f32x2 vv[8];
            computeV(wa, ma, vv);
            f32x2 rw2 = rw;
            #pragma unroll
            for (int dd = 0; dd < 8; ++dd) {
                t12[dd] = pk_fma(rw2, vv[dd], t12[dd]);
                s12[dd] += vv[dd];
                s22[dd] = pk_fma(vv[dd], vv[dd], s22[dd]);
            }
        }
        float t1[16], s1[16], s2[16];
        #pragma unroll
        for (int dd = 0; dd < 8; ++dd) {
            t1[2 * dd] = t12[dd].x; t1[2 * dd + 1] = t12[dd].y;
            s1[2 * dd] = s12[dd].x; s1[2 * dd + 1] = s12[dd].y;
            s2[2 * dd] = s22[dd].x; s2[2 * dd + 1] = s22[dd].y;
        }
        rsum += __shfl_xor(rsum, 32);
        #pragma unroll
        for (int d = 0; d < 16; ++d) {
            t1[d] += __shfl_xor(t1[d], 32);
            s1[d] += __shfl_xor(s1[d], 32);
            s2[d] += __shfl_xor(s2[d], 32);
        }
        if ((t & 32) == 0) {
            atomicAdd(&RsumL[c], rsum);
            #pragma unroll
            for (int d = 0; d < 16; ++d) {
                atomicAdd(&T1L[c * ST + d], t1[d]);
                atomicAdd(&S1L[c * ST + d], s1[d]);
                atomicAdd(&S2L[c * ST + d], s2[d]);
            }
        }
        __syncthreads();
        statsA();
        __syncthreads();
        statsB(1.0f);   // it = 0
        __syncthreads();
    }

    // ---- passes 1,2: fused E-step, TWO i's per trip (batched softmax) ----
    for (int it = 1; it < 3; ++it) {
        f32x2 Mr2[8], i2n[8];   // i2n = -(0.5/var)*log2e (packed, pre-negated)
        #pragma unroll
        for (int dd = 0; dd < 8; ++dd) {
            Mr2[dd].x = ML[c * ST + 2 * dd];
            Mr2[dd].y = ML[c * ST + 2 * dd + 1];
            i2n[dd].x = -I2L[c * ST + 2 * dd];
            i2n[dd].y = -I2L[c * ST + 2 * dd + 1];
        }
        float Kc2 = (constL[c] - KmaxL) * L2E; // exp2 arg <= 0 always
        __syncthreads();                       // all reads done before re-zero
        for (int idx = t; idx < NC * ST; idx += NTHREADS) T1L[idx] = 0.f;
        if (t < NC) RsumL[t] = 0.f;
        __syncthreads();

        f32x2 t12[8];
        #pragma unroll
        for (int dd = 0; dd < 8; ++dd) t12[dd] = 0.f;
        float rsum = 0.f;

        auto quadExp = [&](const f32x2 (&vv)[8]) -> float {
            f32x2 qa = 0.f, qb = 0.f;
            #pragma unroll
            for (int dd = 0; dd < 4; ++dd) {
                f32x2 df = vv[dd] - Mr2[dd];
                qa = pk_fma(df, df * i2n[dd], qa);
            }
            #pragma unroll
            for (int dd = 4; dd < 8; ++dd) {
                f32x2 df = vv[dd] - Mr2[dd];
                qb = pk_fma(df, df * i2n[dd], qb);
            }
            f32x2 qs = qa + qb;
            return exp2f(Kc2 + qs.x + qs.y);   // <= 1; denom >= e^-8: safe
        };

        for (int j = 0; j < IPT; j += 2) {
            const int i0 = iBase + j, i1 = i0 + 1;
            // load both fragments up front (latencies overlap)
            float wa0[16], ma0[16], wa1[16], ma1[16];
            loadFrag(i0, wa0, ma0);
            loadFrag(i1, wa1, ma1);
            float a0 = apL[i0], a1 = apL[i1];
            // two independent chains through V, quad, exp2
            f32x2 vv0[8], vv1[8];
            computeV(wa0, ma0, vv0);
            computeV(wa1, ma1, vv1);
            float ex0 = quadExp(vv0);
            float ex1 = quadExp(vv1);
            // DPP sums (VALU) then BOTH LDS shuffles back-to-back:
            // the second round-trip overlaps the first's latency.
            float ss0 = row_sum16(ex0);
            float ss1 = row_sum16(ex1);
            float sh0 = __shfl_xor(ss0, 16);
            float sh1 = __shfl_xor(ss1, 16);
            float rw0 = ex0 * rcp_fast(ss0 + sh0) * a0;
            float rw1 = ex1 * rcp_fast(ss1 + sh1) * a1;
            rsum += rw0 + rw1;
            f32x2 rw02 = rw0, rw12 = rw1;
            #pragma unroll
            for (int dd = 0; dd < 8; ++dd) {
                t12[dd] = pk_fma(rw02, vv0[dd], t12[dd]);
                t12[dd] = pk_fma(rw12, vv1[dd], t12[dd]);
            }
        }
        float t1[16];
        #pragma unroll
        for (int dd = 0; dd < 8; ++dd) {
            t1[2 * dd] = t12[dd].x; t1[2 * dd + 1] = t12[dd].y;
        }
        rsum += __shfl_xor(rsum, 32);
        #pragma unroll
        for (int d = 0; d < 16; ++d) t1[d] += __shfl_xor(t1[d], 32);
        if ((t & 32) == 0) {
            atomicAdd(&RsumL[c], rsum);
            #pragma unroll
            for (int d = 0; d < 16; ++d) atomicAdd(&T1L[c * ST + d], t1[d]);
        }
        __syncthreads();
        statsA();
        __syncthreads();
        statsB(1.0f + (float)it);   // inv_temp = 1 + it
        __syncthreads();
    }

    // ---- epilogue: out[b,ho,wo,c,0:16]=M, out[...,16]=sigmoid(a_j) ----
    // output stride per capsule is 17 == ST, so ML indexes line up directly.
    for (int idx = t; idx < NC * 17; idx += NTHREADS) {
        int cc = idx / 17;
        int e = idx - cc * 17;
        float val = (e < 16) ? ML[idx] : aoutL[cc];
        out[(size_t)bid * (NC * 17) + idx] = val;
    }
}

extern "C" void kernel_launch(void* const* d_in, const int* in_sizes, int n_in,
                              void* d_out, int out_size, void* d_ws, size_t ws_size,
                              hipStream_t stream) {
    const float* x  = (const float*)d_in[0];
    const float* W  = (const float*)d_in[1];
    const float* bv = (const float*)d_in[2];
    const float* ba = (const float*)d_in[3];
    float* out = (float*)d_out;
    // grid = B*Ho*Wo = 2*12*12 = 288 positions, one block each
    caps_em_kernel<<<288, NTHREADS, 0, stream>>>(x, W, bv, ba, out);
}

// Round 15
// 169.753 us; speedup vs baseline: 1.0350x; 1.0350x over previous
//
#include <hip/hip_runtime.h>
#include <math.h>

// ConvolutionalCapsule with EM routing, fully fused. Round-15 = R14 with the
// permlane16_swap lane-SELECTION INVERSION fixed (R14's only bug):
//   v_permlane16_swap_b32 swaps ODD rows of vdst with EVEN rows of vsrc.
//   Self-swap (both = x): r[0] = even-row values (replicated into odd rows),
//   r[1] = odd-row values (replicated into even rows). Partner of a
//   bit4=0 lane is therefore in r[1], bit4=1 in r[0]:  lo ? r[1] : r[0].
//   R14 selected lo ? r[0] : r[1] => each lane summed its OWN half twice
//   => denominator 2x half-sum => absmax 13.25. (Same inversion explains
//   R2's permlane32 failure; learn_hip T12 verifies permlane32_swap HW
//   semantics with both result words usable.)
// Base = R12 (grid 144, block 1024 = two independent 512-thread units, one
// position each, LDS-staged tile, packed f32x2 math, zero spill,
// harness 169.7us / rocprof 119us). Delta removes the LAST LDS-pipe
// cross-lane op from the hot loop (shfl_xor(16), ~chain-end, 36x/thread).
// Session ledger: nulled = TLP (R9/R10), instr count (R12), LDS-op count
// (R11), spills (R12), W-latency (R8), chain ILP (R13). Wins = removal of
// per-iteration cross-lane LDS links (R6 -48us, R7 -8us). This is the last.
// Proven set carried: Kmax shift, parallel statsA/B, DPP row reduce,
// I2L pre-scaled by log2e + pre-negated, ST=17 bijective banks, packing.
// Unit thread map: c = u&31, isub = u>>5 (0..15), i = isub*18 + j.

#define EPSF 1e-7f
#define KKI 288
#define NC 32
#define NTHREADS 1024
#define UNIT 512
#define IPT 18          // KKI / 16 half-waves per unit
#define ST 17           // padded stride: (17c+d)%32 bijective over c
#define L2E 1.4426950408889634f

typedef float f32x2 __attribute__((ext_vector_type(2)));

__device__ __forceinline__ float rcp_fast(float v) { return __builtin_amdgcn_rcpf(v); }
__device__ __forceinline__ f32x2 pk_fma(f32x2 a, f32x2 b, f32x2 c) {
    return __builtin_elementwise_fma(a, b, c);   // -> v_pk_fma_f32
}

// DPP-based cross-lane (VALU pipe; proven R7)
template <int CTRL>
__device__ __forceinline__ float dpp_mov_f(float x) {
    return __int_as_float(__builtin_amdgcn_update_dpp(
        0, __float_as_int(x), CTRL, 0xF, 0xF, true));
}
__device__ __forceinline__ float row_sum16(float x) {
    x += dpp_mov_f<0xB1>(x);    // quad_perm xor1
    x += dpp_mov_f<0x4E>(x);    // quad_perm xor2
    x += dpp_mov_f<0x124>(x);   // row_ror:4
    x += dpp_mov_f<0x128>(x);   // row_ror:8
    return x;
}
__device__ __forceinline__ float row_max16(float x) {
    x = fmaxf(x, dpp_mov_f<0xB1>(x));
    x = fmaxf(x, dpp_mov_f<0x4E>(x));
    x = fmaxf(x, dpp_mov_f<0x124>(x));
    x = fmaxf(x, dpp_mov_f<0x128>(x));
    return x;
}
// value of lane^16 via VALU permlane16_swap (gfx950); LDS-shfl fallback.
// Self-swap: r[0] = even-row (bit4=0) values, r[1] = odd-row values.
// Partner of bit4=0 lane is in r[1]; of bit4=1 lane in r[0].
__device__ __forceinline__ float partner16(float x, bool lo) {
#if __has_builtin(__builtin_amdgcn_permlane16_swap)
    typedef int v2i __attribute__((ext_vector_type(2)));
    v2i r = __builtin_amdgcn_permlane16_swap(__float_as_int(x), __float_as_int(x),
                                             false, false);
    return __int_as_float(lo ? r[1] : r[0]);   // R14 had this inverted
#else
    (void)lo;
    return __shfl_xor(x, 16);
#endif
}

__global__ __launch_bounds__(NTHREADS)
void caps_em_kernel(const float* __restrict__ x, const float* __restrict__ Wg,
                    const float* __restrict__ beta_v, const float* __restrict__ beta_a,
                    float* __restrict__ out)
{
    // per-unit LDS (H = 0/1). ~31KB each.
    __shared__ float MpL[2][KKI * 16];
    __shared__ float apL[2][KKI];
    __shared__ float T1L[2][NC * ST];
    __shared__ float S1L[2][NC * ST];
    __shared__ float S2L[2][NC * ST];
    __shared__ float ML[2][NC * ST];
    __shared__ float I2L[2][NC * ST];   // 0.5/var * log2e (pre-scaled)
    __shared__ float RsumL[2][NC];
    __shared__ float constL[2][NC];
    __shared__ float slogL[2][NC];
    __shared__ float costL[2][NC];
    __shared__ float aoutL[2][NC];
    __shared__ float KmaxL[2];

    const int t = threadIdx.x;
    const int H = t >> 9;                 // unit id (waves never straddle)
    const int u = t & 511;                // unit-local thread id
    const int pos = blockIdx.x * 2 + H;   // 0..287 = b*144 + ho*12 + wo
    const int b = pos / 144;
    const int rem = pos - b * 144;
    const int ho = rem / 12;
    const int wo = rem - ho * 12;

    const int c = u & 31;
    const int isub = u >> 5;              // 0..15
    const int iBase = isub * IPT;
    const bool lo16 = (u & 16) == 0;      // lane bit 4

    // ---- stage patch tile for this unit's position ----
    for (int idx = u; idx < KKI * 17; idx += UNIT) {
        int i = idx / 17;
        int e = idx - i * 17;
        int p = i >> 5, cin = i & 31;
        int di = p / 3, dj = p - di * 3;
        float vx = x[(((b * 14 + (ho + di)) * 14 + (wo + dj)) * 32 + cin) * 17 + e];
        if (e < 16) MpL[H][i * 16 + e] = vx; else apL[H][i] = vx;
    }
    for (int idx = u; idx < NC * ST; idx += UNIT) { T1L[H][idx] = 0.f; S1L[H][idx] = 0.f; S2L[H][idx] = 0.f; }
    if (u < NC) RsumL[H][u] = 0.f;
    __syncthreads();

    // stats A: 512 unit-threads, one per (cc = u>>4, d = u&15);
    // d = lane bits 0-3 => pure-DPP row sum for slog.
    auto statsA = [&]() {
        const int cc = u >> 4, d = u & 15;
        float rsum = RsumL[H][cc];
        float m = T1L[H][cc * ST + d] * rcp_fast(rsum);
        float var = S2L[H][cc * ST + d] - 2.f * m * S1L[H][cc * ST + d] + 288.f * m * m;
        var = fmaxf(var, 0.f);
        float lg = logf(sqrtf(var) + EPSF);
        ML[H][cc * ST + d] = m;
        I2L[H][cc * ST + d] = 0.5f * L2E * rcp_fast(var);
        float sl = row_sum16(lg);
        if (d == 0) {
            slogL[H][cc] = sl;
            costL[H][cc] = rsum * (16.f * beta_v[cc] + sl);
        }
    };
    // stats B: cross-capsule mean/std + activation + Kmax (32 unit-threads).
    auto statsB = [&](float inv_temp) {
        if (u < 32) {
            float cost = costL[H][u];
            float csum = row_sum16(cost); csum += __shfl_xor(csum, 16);
            float c_mean = csum * 0.03125f;
            float diff = cost - c_mean;
            float dsq = row_sum16(diff * diff); dsq += __shfl_xor(dsq, 16);
            float c_stdv = sqrtf(dsq * 0.03125f);
            float a_cost = beta_a[u] + (c_mean - cost) * rcp_fast(c_stdv + EPSF);
            float a_j = 1.f / (1.f + expf(-inv_temp * a_cost));
            float kc = logf(a_j + EPSF) - slogL[H][u];
            constL[H][u] = kc;
            aoutL[H][u] = 1.f / (1.f + expf(-a_j));
            float km = row_max16(kc); km = fmaxf(km, __shfl_xor(km, 16));
            if (u == 0) KmaxL[H] = km;
        }
    };

    // packed vote compute: vv[p*2+rr] = (v[p*4+2rr], v[p*4+2rr+1])
    auto computeV = [&](const float (&wa)[16], const float (&ma)[16], f32x2 (&vv)[8]) {
        const f32x2* w2 = (const f32x2*)wa;   // w2[q*2+rr]
        #pragma unroll
        for (int p = 0; p < 4; ++p) {
            f32x2 m0 = ma[p * 4 + 0], m1 = ma[p * 4 + 1];
            f32x2 m2 = ma[p * 4 + 2], m3 = ma[p * 4 + 3];
            #pragma unroll
            for (int rr = 0; rr < 2; ++rr) {
                f32x2 acc = m0 * w2[0 * 2 + rr];
                acc = pk_fma(m1, w2[1 * 2 + rr], acc);
                acc = pk_fma(m2, w2[2 * 2 + rr], acc);
                acc = pk_fma(m3, w2[3 * 2 + rr], acc);
                vv[p * 2 + rr] = acc;
            }
        }
    };

    // ---- pass 0: R uniform 1/32 -> Rw = ap/32; also build S1,S2 ----
    {
        f32x2 t12[8], s12[8], s22[8];
        #pragma unroll
        for (int dd = 0; dd < 8; ++dd) { t12[dd] = 0.f; s12[dd] = 0.f; s22[dd] = 0.f; }
        float rsum = 0.f;
        for (int j = 0; j < IPT; ++j) {
            const int i = iBase + j;
            float wa[16], ma[16];
            const float4* w4 = (const float4*)(Wg + ((size_t)((i << 5) + c) << 4));
            ((float4*)wa)[0] = w4[0]; ((float4*)wa)[1] = w4[1];
            ((float4*)wa)[2] = w4[2]; ((float4*)wa)[3] = w4[3];
            const float4* mp4 = (const float4*)(&MpL[H][i << 4]);
            ((float4*)ma)[0] = mp4[0]; ((float4*)ma)[1] = mp4[1];
            ((float4*)ma)[2] = mp4[2]; ((float4*)ma)[3] = mp4[3];
            float rw = apL[H][i] * 0.03125f;
            rsum += rw;
            f32x2 vv[8];
            computeV(wa, ma, vv);
            f32x2 rw2 = rw;
            #pragma unroll
            for (int dd = 0; dd < 8; ++dd) {
                t12[dd] = pk_fma(rw2, vv[dd], t12[dd]);
                s12[dd] += vv[dd];
                s22[dd] = pk_fma(vv[dd], vv[dd], s22[dd]);
            }
        }
        // unpack, combine partner half-waves (lane^32 shares c), then atomics
        float t1[16], s1[16], s2[16];
        #pragma unroll
        for (int dd = 0; dd < 8; ++dd) {
            t1[2 * dd] = t12[dd].x; t1[2 * dd + 1] = t12[dd].y;
            s1[2 * dd] = s12[dd].x; s1[2 * dd + 1] = s12[dd].y;
            s2[2 * dd] = s22[dd].x; s2[2 * dd + 1] = s22[dd].y;
        }
        rsum += __shfl_xor(rsum, 32);
        #pragma unroll
        for (int d = 0; d < 16; ++d) {
            t1[d] += __shfl_xor(t1[d], 32);
            s1[d] += __shfl_xor(s1[d], 32);
            s2[d] += __shfl_xor(s2[d], 32);
        }
        if ((u & 32) == 0) {
            atomicAdd(&RsumL[H][c], rsum);
            #pragma unroll
            for (int d = 0; d < 16; ++d) {
                atomicAdd(&T1L[H][c * ST + d], t1[d]);
                atomicAdd(&S1L[H][c * ST + d], s1[d]);
                atomicAdd(&S2L[H][c * ST + d], s2[d]);
            }
        }
        __syncthreads();
        statsA();
        __syncthreads();
        statsB(1.0f);   // it = 0
        __syncthreads();
    }

    // ---- passes 1,2: fused E-step (softmax over c, in-register) + M-step ----
    for (int it = 1; it < 3; ++it) {
        f32x2 Mr2[8], i2n[8];   // i2n = -(0.5/var)*log2e  (packed, pre-negated)
        #pragma unroll
        for (int dd = 0; dd < 8; ++dd) {
            Mr2[dd].x = ML[H][c * ST + 2 * dd];
            Mr2[dd].y = ML[H][c * ST + 2 * dd + 1];
            i2n[dd].x = -I2L[H][c * ST + 2 * dd];
            i2n[dd].y = -I2L[H][c * ST + 2 * dd + 1];
        }
        float Kc2 = (constL[H][c] - KmaxL[H]) * L2E;  // exp2 arg <= 0 always
        __syncthreads();                       // all reads done before re-zero
        for (int idx = u; idx < NC * ST; idx += UNIT) T1L[H][idx] = 0.f;
        if (u < NC) RsumL[H][u] = 0.f;
        __syncthreads();

        f32x2 t12[8];
        #pragma unroll
        for (int dd = 0; dd < 8; ++dd) t12[dd] = 0.f;
        float rsum = 0.f;
        for (int j = 0; j < IPT; ++j) {
            const int i = iBase + j;
            float wa[16], ma[16];
            const float4* w4 = (const float4*)(Wg + ((size_t)((i << 5) + c) << 4));
            ((float4*)wa)[0] = w4[0]; ((float4*)wa)[1] = w4[1];
            ((float4*)wa)[2] = w4[2]; ((float4*)wa)[3] = w4[3];
            const float4* mp4 = (const float4*)(&MpL[H][i << 4]);
            ((float4*)ma)[0] = mp4[0]; ((float4*)ma)[1] = mp4[1];
            ((float4*)ma)[2] = mp4[2]; ((float4*)ma)[3] = mp4[3];
            float a_i = apL[H][i];
            f32x2 vv[8];
            computeV(wa, ma, vv);
            // quadratic: two 4-deep packed chains; i2n pre-negated
            f32x2 qa = 0.f, qb = 0.f;
            #pragma unroll
            for (int dd = 0; dd < 4; ++dd) {
                f32x2 df = vv[dd] - Mr2[dd];
                qa = pk_fma(df, df * i2n[dd], qa);
            }
            #pragma unroll
            for (int dd = 4; dd < 8; ++dd) {
                f32x2 df = vv[dd] - Mr2[dd];
                qb = pk_fma(df, df * i2n[dd], qb);
            }
            f32x2 qs = qa + qb;
            float ex = exp2f(Kc2 + qs.x + qs.y); // <= 1; denom >= e^-8: safe
            // softmax denominator over the 32 caps of this half-wave:
            // DPP row sum (lane bits 0-3) + VALU permlane16_swap (bit 4) —
            // the hot loop is now entirely LDS-pipe-free for cross-lane.
            float ssum = row_sum16(ex);
            ssum += partner16(ssum, lo16);
            float rw = ex * rcp_fast(ssum) * a_i;
            rsum += rw;
            f32x2 rw2 = rw;
            #pragma unroll
            for (int dd = 0; dd < 8; ++dd) t12[dd] = pk_fma(rw2, vv[dd], t12[dd]);
        }
        float t1[16];
        #pragma unroll
        for (int dd = 0; dd < 8; ++dd) {
            t1[2 * dd] = t12[dd].x; t1[2 * dd + 1] = t12[dd].y;
        }
        rsum += __shfl_xor(rsum, 32);
        #pragma unroll
        for (int d = 0; d < 16; ++d) t1[d] += __shfl_xor(t1[d], 32);
        if ((u & 32) == 0) {
            atomicAdd(&RsumL[H][c], rsum);
            #pragma unroll
            for (int d = 0; d < 16; ++d) atomicAdd(&T1L[H][c * ST + d], t1[d]);
        }
        __syncthreads();
        statsA();
        __syncthreads();
        statsB(1.0f + (float)it);   // inv_temp = 1 + it
        __syncthreads();
    }

    // ---- epilogue: out[pos,c,0:16]=M, out[pos,c,16]=sigmoid(a_j) ----
    // output stride per capsule is 17 == ST, so ML indexes line up directly.
    for (int idx = u; idx < NC * 17; idx += UNIT) {
        int cc = idx / 17;
        int e = idx - cc * 17;
        float val = (e < 16) ? ML[H][idx] : aoutL[H][cc];
        out[(size_t)pos * (NC * 17) + idx] = val;
    }
}

extern "C" void kernel_launch(void* const* d_in, const int* in_sizes, int n_in,
                              void* d_out, int out_size, void* d_ws, size_t ws_size,
                              hipStream_t stream) {
    const float* x  = (const float*)d_in[0];
    const float* W  = (const float*)d_in[1];
    const float* bv = (const float*)d_in[2];
    const float* ba = (const float*)d_in[3];
    float* out = (float*)d_out;
    // 288 positions, 2 per block => grid 144 <= 256 CUs: single dispatch round
    caps_em_kernel<<<144, NTHREADS, 0, stream>>>(x, W, bv, ba, out);
}